// Round 4
// baseline (8242.547 us; speedup 1.0000x reference)
//
#include <hip/hip_runtime.h>
#include <hip/hip_bf16.h>

#define D 1024
#define NH 16
#define HD 64
#define NTOK 16385
#define NPATCH 16384

// ---------------- patchify: x[B,C,H,W] -> patches[16384, 768] ----------------
__global__ __launch_bounds__(256) void patchify_kernel(const float* __restrict__ x,
                                                       float* __restrict__ patches) {
    int gid = blockIdx.x * 256 + threadIdx.x;      // each thread: 4 consecutive k
    int e = gid * 4;                               // element index into [16384*768]
    int n = e / 768;
    int k = e - n * 768;
    int c = k >> 8;          // /256
    int rem = k & 255;
    int i = rem >> 4;
    int jj = rem & 15;
    int b = n >> 10;
    int hp = (n & 1023) >> 5;
    int wp = n & 31;
    const float* src = x + (((size_t)(b * 3 + c) * 512 + hp * 16 + i) * 512 + wp * 16 + jj);
    *(float4*)(patches + (size_t)e) = *(const float4*)src;
}

// ---------------- cls token -> emb row 0 ----------------
__global__ __launch_bounds__(256) void cls_kernel(const float* __restrict__ cls,
                                                  float* __restrict__ emb) {
    int j = threadIdx.x * 4;
    *(float4*)(emb + j) = *(const float4*)(cls + j);
}

// ---------------- zero 1024 floats ----------------
__global__ __launch_bounds__(256) void zero_kernel(float* __restrict__ p) {
    p[blockIdx.x * 256 + threadIdx.x] = 0.f;
}

// ---------------- per-layer scalar weight sums (LDS tree reduce) ----------------
__global__ __launch_bounds__(256) void sums6_kernel(const float* w0, const float* w1,
                                                    const float* w2, const float* w3,
                                                    const float* w4, const float* w5,
                                                    float* __restrict__ scal) {
    __shared__ float sh[256];
    const float* ptrs[6] = {w0, w1, w2, w3, w4, w5};
    const float* w = ptrs[blockIdx.x];
    const int tid = threadIdx.x;
    float s = 0.f;
    for (int i = tid; i < NH * HD * HD; i += 256) s += w[i];
    sh[tid] = s;
    __syncthreads();
    for (int st = 128; st > 0; st >>= 1) {
        if (tid < st) sh[tid] += sh[tid + st];
        __syncthreads();
    }
    if (tid == 0) scal[blockIdx.x] = sh[0];
}

// ---------------- LayerNorm, two-pass (mu then sum (x-mu)^2), LDS reduce ----------------
__global__ __launch_bounds__(256) void ln_kernel(const float* __restrict__ X,
                                                 const float* __restrict__ g,
                                                 const float* __restrict__ bt,
                                                 float* __restrict__ Y) {
    __shared__ float sh[256];
    const int n = blockIdx.x;
    const int tid = threadIdx.x;
    const float4 v = *(const float4*)(X + (size_t)n * D + tid * 4);
    sh[tid] = v.x + v.y + v.z + v.w;
    __syncthreads();
    for (int st = 128; st > 0; st >>= 1) {
        if (tid < st) sh[tid] += sh[tid + st];
        __syncthreads();
    }
    const float mu = sh[0] * (1.f / D);
    __syncthreads();
    float d0 = v.x - mu, d1 = v.y - mu, d2 = v.z - mu, d3 = v.w - mu;
    sh[tid] = d0 * d0 + d1 * d1 + d2 * d2 + d3 * d3;
    __syncthreads();
    for (int st = 128; st > 0; st >>= 1) {
        if (tid < st) sh[tid] += sh[tid + st];
        __syncthreads();
    }
    const float var = sh[0] * (1.f / D);
    const float rs = rsqrtf(var + 1e-5f);
    const float4 gg = *(const float4*)(g + tid * 4);
    const float4 bb = *(const float4*)(bt + tid * 4);
    float4 o4;
    o4.x = d0 * rs * gg.x + bb.x;
    o4.y = d1 * rs * gg.y + bb.y;
    o4.z = d2 * rs * gg.z + bb.z;
    o4.w = d3 * rs * gg.w + bb.w;
    *(float4*)(Y + (size_t)n * D + tid * 4) = o4;
}

// ---------------- per-token per-head sumsq of Y ----------------
__global__ __launch_bounds__(256) void nrm_kernel(const float* __restrict__ Y,
                                                  float* __restrict__ nrm) {
    __shared__ float sh[256];
    const int n = blockIdx.x;
    const int tid = threadIdx.x;
    const float4 v = *(const float4*)(Y + (size_t)n * D + tid * 4);
    sh[tid] = v.x * v.x + v.y * v.y + v.z * v.z + v.w * v.w;
    __syncthreads();
    if (tid < NH) {
        float s = 0.f;
        for (int u = 0; u < 16; ++u) s += sh[tid * 16 + u];
        nrm[(size_t)n * NH + tid] = s;
    }
}

// ---------------- leaky-relu + LayerNorm (block tail), two-pass ----------------
__global__ __launch_bounds__(256) void post_kernel(const float* __restrict__ X,
                                                   const float* __restrict__ g,
                                                   const float* __restrict__ bt,
                                                   float* __restrict__ Y) {
    __shared__ float sh[256];
    const int n = blockIdx.x;
    const int tid = threadIdx.x;
    float4 v = *(const float4*)(X + (size_t)n * D + tid * 4);
    v.x = v.x > 0.f ? v.x : 0.01f * v.x;
    v.y = v.y > 0.f ? v.y : 0.01f * v.y;
    v.z = v.z > 0.f ? v.z : 0.01f * v.z;
    v.w = v.w > 0.f ? v.w : 0.01f * v.w;
    sh[tid] = v.x + v.y + v.z + v.w;
    __syncthreads();
    for (int st = 128; st > 0; st >>= 1) {
        if (tid < st) sh[tid] += sh[tid + st];
        __syncthreads();
    }
    const float mu = sh[0] * (1.f / D);
    __syncthreads();
    float d0 = v.x - mu, d1 = v.y - mu, d2 = v.z - mu, d3 = v.w - mu;
    sh[tid] = d0 * d0 + d1 * d1 + d2 * d2 + d3 * d3;
    __syncthreads();
    for (int st = 128; st > 0; st >>= 1) {
        if (tid < st) sh[tid] += sh[tid + st];
        __syncthreads();
    }
    const float var = sh[0] * (1.f / D);
    const float rs = rsqrtf(var + 1e-5f);
    const float4 gg = *(const float4*)(g + tid * 4);
    const float4 bb = *(const float4*)(bt + tid * 4);
    float4 o4;
    o4.x = d0 * rs * gg.x + bb.x;
    o4.y = d1 * rs * gg.y + bb.y;
    o4.z = d2 * rs * gg.z + bb.z;
    o4.w = d3 * rs * gg.w + bb.w;
    *(float4*)(Y + (size_t)n * D + tid * 4) = o4;
}

// ---------------- temporal softmax: 16384 (p,h) pairs, 17 keys (per-thread) ----------------
__global__ __launch_bounds__(256) void attn_t_kernel(const float* __restrict__ nrm,
                                                     const float* __restrict__ scal,
                                                     float* __restrict__ attw) {
    int idx = blockIdx.x * 256 + threadIdx.x;   // p*16 + h
    int p = idx >> 4, h = idx & 15;
    float s = scal[0] * scal[1] * 0.125f;       // sq*sk/sqrt(64)
    float l0 = s * nrm[h];
    float lg[16];
    float mx = l0;
#pragma unroll
    for (int b = 0; b < 16; ++b) {
        float v = s * nrm[(size_t)(1 + p * 16 + b) * NH + h];
        lg[b] = v;
        mx = fmaxf(mx, v);
    }
    float e0 = expf(l0 - mx), Z = e0;
    float eb[16];
#pragma unroll
    for (int b = 0; b < 16; ++b) { eb[b] = expf(lg[b] - mx); Z += eb[b]; }
    float inv = 1.f / Z;
    float* o = attw + (size_t)idx * 17;
    o[0] = e0 * inv;
#pragma unroll
    for (int b = 0; b < 16; ++b) o[1 + b] = eb[b] * inv;
}

// ---------------- spatial softmax: 256 (b,h) blocks, 1025 keys (LDS reduce) ----------------
__global__ __launch_bounds__(256) void attn_s_kernel(const float* __restrict__ nrm,
                                                     const float* __restrict__ scal,
                                                     float* __restrict__ attw) {
    __shared__ float sh[256];
    int bh = blockIdx.x;
    int b = bh >> 4, h = bh & 15;
    int tid = threadIdx.x;
    float s = scal[3] * scal[4] * 0.125f;
    float l0 = s * nrm[h];
    float lv[4];
    float mx = l0;
#pragma unroll
    for (int r = 0; r < 4; ++r) {
        lv[r] = s * nrm[(size_t)(1 + b * 1024 + tid + r * 256) * NH + h];
        mx = fmaxf(mx, lv[r]);
    }
    sh[tid] = mx;
    __syncthreads();
    for (int st = 128; st > 0; st >>= 1) {
        if (tid < st) sh[tid] = fmaxf(sh[tid], sh[tid + st]);
        __syncthreads();
    }
    mx = sh[0];
    __syncthreads();
    float ev[4];
    float z = (tid == 0) ? expf(l0 - mx) : 0.f;
#pragma unroll
    for (int r = 0; r < 4; ++r) { ev[r] = expf(lv[r] - mx); z += ev[r]; }
    sh[tid] = z;
    __syncthreads();
    for (int st = 128; st > 0; st >>= 1) {
        if (tid < st) sh[tid] += sh[tid + st];
        __syncthreads();
    }
    float inv = 1.f / sh[0];
    float* o = attw + (size_t)bh * 1025;
    if (tid == 0) o[0] = expf(l0 - mx) * inv;
#pragma unroll
    for (int r = 0; r < 4; ++r) o[1 + tid + r * 256] = ev[r] * inv;
}

// ---------------- build pre-projection matrix (temporal) ----------------
__global__ __launch_bounds__(256) void build_t_kernel(const float* __restrict__ ln,
                                                      const float* __restrict__ attw,
                                                      const float* __restrict__ scal,
                                                      float* __restrict__ pre,
                                                      float* __restrict__ tokacc) {
    const float sv = scal[2];
    const int j = blockIdx.y * 256 + threadIdx.x;
    const int h = j >> 6;
    const float l0 = ln[j];
    float tacc = 0.f;
    const int n0 = 1 + blockIdx.x * 64;
    for (int r = 0; r < 64; ++r) {
        int n = n0 + r;
        int pb = n - 1;
        int p = pb >> 4, bb = pb & 15;
        const float* aw = attw + (size_t)(p * NH + h) * 17;
        float w0 = aw[0], wb = aw[1 + bb];
        float xv = ln[(size_t)n * D + j];
        pre[(size_t)n * D + j] = sv * (wb * xv + w0 * l0);
        tacc += w0 * xv;
    }
    atomicAdd(&tokacc[j], tacc);
}

// ---------------- build pre-projection matrix (spatial) ----------------
__global__ __launch_bounds__(256) void build_s_kernel(const float* __restrict__ ln,
                                                      const float* __restrict__ attw,
                                                      const float* __restrict__ scal,
                                                      float* __restrict__ pre,
                                                      float* __restrict__ tokacc) {
    const float sv = scal[5];
    const int j = blockIdx.y * 256 + threadIdx.x;
    const int h = j >> 6;
    const float l0 = ln[j];
    float tacc = 0.f;
    const int n0 = 1 + blockIdx.x * 64;
    for (int r = 0; r < 64; ++r) {
        int n = n0 + r;
        int pb = n - 1;
        int b = pb >> 10, p = pb & 1023;
        const float* aw = attw + (size_t)(b * NH + h) * 1025;
        float w0 = aw[0], wp = aw[1 + p];
        float xv = ln[(size_t)n * D + j];
        pre[(size_t)n * D + j] = sv * (wp * xv + w0 * l0);
        tacc += w0 * xv;
    }
    atomicAdd(&tokacc[j], tacc);
}

// ---------------- finalize cls row of pre ----------------
__global__ __launch_bounds__(256) void fin_tok_kernel(const float* __restrict__ ln0,
                                                      const float* __restrict__ tokacc,
                                                      const float* __restrict__ scal,
                                                      int svidx,
                                                      float* __restrict__ pre0) {
    int j = blockIdx.x * 256 + threadIdx.x;
    pre0[j] = scal[svidx] * (ln0[j] + tokacc[j]);
}

// ---------------- f32 tiled GEMM: C = A @ B(^T) [+bias] + E ----------------
template <int TRANSB, int HAS_BIAS>
__global__ __launch_bounds__(256) void gemm_f32(const float* __restrict__ A,
                                                const float* __restrict__ W,
                                                const float* __restrict__ bias,
                                                const float* __restrict__ E,
                                                float* __restrict__ C,
                                                int M, int N, int K) {
    __shared__ float As[16][68];
    __shared__ float Bs[16][68];
    const int tid = threadIdx.x;
    const int tx = tid & 15, ty = tid >> 4;
    const int c0 = blockIdx.x * 64, r0 = blockIdx.y * 64;
    float acc[4][4] = {};
    const int rowa = tid >> 2, ka = (tid & 3) * 4;
    for (int k0 = 0; k0 < K; k0 += 16) {
        int gr = r0 + rowa;
        float4 av = make_float4(0.f, 0.f, 0.f, 0.f);
        if (gr < M) av = *(const float4*)(A + (size_t)gr * K + k0 + ka);
        As[ka + 0][rowa] = av.x; As[ka + 1][rowa] = av.y;
        As[ka + 2][rowa] = av.z; As[ka + 3][rowa] = av.w;
        if (TRANSB) {
            int col = tid >> 2, kb = (tid & 3) * 4;
            float4 bv = *(const float4*)(W + (size_t)(c0 + col) * K + k0 + kb);
            Bs[kb + 0][col] = bv.x; Bs[kb + 1][col] = bv.y;
            Bs[kb + 2][col] = bv.z; Bs[kb + 3][col] = bv.w;
        } else {
            int kb = tid >> 4, col = (tid & 15) * 4;
            float4 bv = *(const float4*)(W + (size_t)(k0 + kb) * N + c0 + col);
            Bs[kb][col + 0] = bv.x; Bs[kb][col + 1] = bv.y;
            Bs[kb][col + 2] = bv.z; Bs[kb][col + 3] = bv.w;
        }
        __syncthreads();
#pragma unroll
        for (int kk = 0; kk < 16; ++kk) {
            float4 a = *(const float4*)(&As[kk][ty * 4]);
            float4 b = *(const float4*)(&Bs[kk][tx * 4]);
            acc[0][0] += a.x * b.x; acc[0][1] += a.x * b.y; acc[0][2] += a.x * b.z; acc[0][3] += a.x * b.w;
            acc[1][0] += a.y * b.x; acc[1][1] += a.y * b.y; acc[1][2] += a.y * b.z; acc[1][3] += a.y * b.w;
            acc[2][0] += a.z * b.x; acc[2][1] += a.z * b.y; acc[2][2] += a.z * b.z; acc[2][3] += a.z * b.w;
            acc[3][0] += a.w * b.x; acc[3][1] += a.w * b.y; acc[3][2] += a.w * b.z; acc[3][3] += a.w * b.w;
        }
        __syncthreads();
    }
#pragma unroll
    for (int i2 = 0; i2 < 4; ++i2) {
        int r = r0 + ty * 4 + i2;
        if (r >= M) continue;
        int c = c0 + tx * 4;
        float4 v;
        v.x = acc[i2][0]; v.y = acc[i2][1]; v.z = acc[i2][2]; v.w = acc[i2][3];
        if (HAS_BIAS) {
            v.x += bias[c]; v.y += bias[c + 1]; v.z += bias[c + 2]; v.w += bias[c + 3];
        }
        float4 ev = *(const float4*)(E + (size_t)r * N + c);
        v.x += ev.x; v.y += ev.y; v.z += ev.z; v.w += ev.w;
        *(float4*)(C + (size_t)r * N + c) = v;
    }
}

extern "C" void kernel_launch(void* const* d_in, const int* in_sizes, int n_in,
                              void* d_out, int out_size, void* d_ws, size_t ws_size,
                              hipStream_t stream) {
    const float* x       = (const float*)d_in[0];
    const float* cls     = (const float*)d_in[1];
    const float* w_embed = (const float*)d_in[2];
    const float* pos_enc = (const float*)d_in[3];
    const float* ln_t_g  = (const float*)d_in[4];
    const float* ln_t_b  = (const float*)d_in[5];
    const float* wq_t    = (const float*)d_in[6];
    const float* wk_t    = (const float*)d_in[7];
    const float* wv_t    = (const float*)d_in[8];
    const float* wt_t    = (const float*)d_in[9];
    const float* ln_s_g  = (const float*)d_in[10];
    const float* ln_s_b  = (const float*)d_in[11];
    const float* wq_s    = (const float*)d_in[12];
    const float* wk_s    = (const float*)d_in[13];
    const float* wv_s    = (const float*)d_in[14];
    const float* wt_s    = (const float*)d_in[15];
    const float* ln_m_g  = (const float*)d_in[16];
    const float* ln_m_b  = (const float*)d_in[17];
    const float* mlp_w   = (const float*)d_in[18];
    const float* mlp_b   = (const float*)d_in[19];
    const float* out_g   = (const float*)d_in[20];
    const float* out_b   = (const float*)d_in[21];

    const size_t BIG = (size_t)NTOK * D;
    float* ws = (float*)d_ws;
    float* bufA = ws;
    float* bufB = bufA + BIG;
    float* bufC = bufB + BIG;
    float* nrm = bufC + BIG;                       // NTOK*NH
    float* attw = nrm + (size_t)NTOK * NH;         // 278528 max
    float* tokacc = attw + 278528;                 // 1024
    float* scal = tokacc + 1024;                   // 8
    size_t need = (size_t)(scal + 8 - ws) * sizeof(float);
    if (ws_size < need) return;   // insufficient scratch; fail visibly

    float* fout = (float*)d_out;  // reference output dtype is float32

    // embed
    patchify_kernel<<<12288, 256, 0, stream>>>(x, bufC);
    cls_kernel<<<1, 256, 0, stream>>>(cls, bufA);
    gemm_f32<1, 0><<<dim3(16, 256), 256, 0, stream>>>(bufC, w_embed, nullptr, pos_enc,
                                                      bufA + D, NPATCH, D, 768);

    dim3 gemm_grid(16, (NTOK + 63) / 64);
    for (int l = 0; l < 4; ++l) {
        const size_t oW = (size_t)l * D * D;
        const size_t oS = (size_t)l * NH * HD * HD;
        const size_t oD = (size_t)l * D;
        sums6_kernel<<<6, 256, 0, stream>>>(wq_t + oS, wk_t + oS, wv_t + oS,
                                            wq_s + oS, wk_s + oS, wv_s + oS, scal);
        // temporal
        ln_kernel<<<NTOK, 256, 0, stream>>>(bufA, ln_t_g + oD, ln_t_b + oD, bufB);
        nrm_kernel<<<NTOK, 256, 0, stream>>>(bufB, nrm);
        zero_kernel<<<4, 256, 0, stream>>>(tokacc);
        attn_t_kernel<<<64, 256, 0, stream>>>(nrm, scal, attw);
        build_t_kernel<<<dim3(256, 4), 256, 0, stream>>>(bufB, attw, scal, bufC, tokacc);
        fin_tok_kernel<<<4, 256, 0, stream>>>(bufB, tokacc, scal, 2, bufC);
        gemm_f32<0, 0><<<gemm_grid, 256, 0, stream>>>(bufC, wt_t + oW, nullptr, bufA,
                                                      bufB, NTOK, D, D);
        // spatial
        ln_kernel<<<NTOK, 256, 0, stream>>>(bufB, ln_s_g + oD, ln_s_b + oD, bufC);
        nrm_kernel<<<NTOK, 256, 0, stream>>>(bufC, nrm);
        zero_kernel<<<4, 256, 0, stream>>>(tokacc);
        attn_s_kernel<<<256, 256, 0, stream>>>(nrm, scal, attw);
        build_s_kernel<<<dim3(256, 4), 256, 0, stream>>>(bufC, attw, scal, bufA, tokacc);
        fin_tok_kernel<<<4, 256, 0, stream>>>(bufC, tokacc, scal, 5, bufA);
        gemm_f32<0, 0><<<gemm_grid, 256, 0, stream>>>(bufA, wt_s + oW, nullptr, bufB,
                                                      bufC, NTOK, D, D);
        // mlp + tail
        ln_kernel<<<NTOK, 256, 0, stream>>>(bufC, ln_m_g + oD, ln_m_b + oD, bufA);
        gemm_f32<1, 1><<<gemm_grid, 256, 0, stream>>>(bufA, mlp_w + oW, mlp_b + oD, bufC,
                                                      bufB, NTOK, D, D);
        // final layer writes the model output (f32) straight to d_out
        post_kernel<<<NTOK, 256, 0, stream>>>(bufB, out_g + oD, out_b + oD,
                                              (l == 3) ? fout : bufA);
    }
}

// Round 7
// 3557.146 us; speedup vs baseline: 2.3172x; 2.3172x over previous
//
#include <hip/hip_runtime.h>
#include <hip/hip_bf16.h>

#define D 1024
#define NH 16
#define HD 64
#define NTOK 16385
#define NPATCH 16384

typedef __bf16 bf16_t;
typedef __attribute__((ext_vector_type(8))) __bf16 bf16x8;
typedef __attribute__((ext_vector_type(4))) float f32x4;

__device__ __forceinline__ ushort f2b(float f) {
    union { float f; uint32_t u; } v; v.f = f;
    return (ushort)((v.u + 0x7FFFu + ((v.u >> 16) & 1u)) >> 16);
}
__device__ __forceinline__ float b2f(ushort u) {
    union { uint32_t u; float f; } v; v.u = ((uint32_t)u) << 16;
    return v.f;
}

__device__ __forceinline__ void gload_lds16(const ushort* g, ushort* l) {
    __builtin_amdgcn_global_load_lds(
        (const __attribute__((address_space(1))) void*)g,
        (__attribute__((address_space(3))) void*)l, 16, 0, 0);
}

// ---------------- patchify: x[B,C,H,W] -> hi/lo bf16 patches[16384,768] ----------------
__global__ __launch_bounds__(256) void patchify_kernel(const float* __restrict__ x,
                                                       ushort* __restrict__ pH,
                                                       ushort* __restrict__ pL) {
    int gid = blockIdx.x * 256 + threadIdx.x;
    int e = gid * 4;
    int n = e / 768;
    int k = e - n * 768;
    int c = k >> 8;
    int rem = k & 255;
    int i = rem >> 4;
    int jj = rem & 15;
    int b = n >> 10;
    int hp = (n & 1023) >> 5;
    int wp = n & 31;
    const float4 v = *(const float4*)(x + (((size_t)(b * 3 + c) * 512 + hp * 16 + i) * 512 + wp * 16 + jj));
    ushort4 h, l;
    h.x = f2b(v.x); l.x = f2b(v.x - b2f(h.x));
    h.y = f2b(v.y); l.y = f2b(v.y - b2f(h.y));
    h.z = f2b(v.z); l.z = f2b(v.z - b2f(h.z));
    h.w = f2b(v.w); l.w = f2b(v.w - b2f(h.w));
    *(ushort4*)(pH + (size_t)e) = h;
    *(ushort4*)(pL + (size_t)e) = l;
}

// ---------------- cls token -> emb row 0 ----------------
__global__ __launch_bounds__(256) void cls_kernel(const float* __restrict__ cls,
                                                  float* __restrict__ emb) {
    int j = threadIdx.x * 4;
    *(float4*)(emb + j) = *(const float4*)(cls + j);
}

// ---------------- zero 1024 floats ----------------
__global__ __launch_bounds__(256) void zero_kernel(float* __restrict__ p) {
    p[blockIdx.x * 256 + threadIdx.x] = 0.f;
}

// ---------------- per-layer scalar weight sums ----------------
__global__ __launch_bounds__(256) void sums6_kernel(const float* w0, const float* w1,
                                                    const float* w2, const float* w3,
                                                    const float* w4, const float* w5,
                                                    float* __restrict__ scal) {
    __shared__ float sh[256];
    const float* ptrs[6] = {w0, w1, w2, w3, w4, w5};
    const float* w = ptrs[blockIdx.x];
    const int tid = threadIdx.x;
    float s = 0.f;
    for (int i = tid; i < NH * HD * HD; i += 256) s += w[i];
    sh[tid] = s;
    __syncthreads();
    for (int st = 128; st > 0; st >>= 1) {
        if (tid < st) sh[tid] += sh[tid + st];
        __syncthreads();
    }
    if (tid == 0) scal[blockIdx.x] = sh[0];
}

// ---------------- LayerNorm two-pass -> hi/lo bf16 planes ----------------
__global__ __launch_bounds__(256) void ln_split_kernel(const float* __restrict__ X,
                                                       const float* __restrict__ g,
                                                       const float* __restrict__ bt,
                                                       ushort* __restrict__ YH,
                                                       ushort* __restrict__ YL) {
    __shared__ float sh[256];
    const int n = blockIdx.x;
    const int tid = threadIdx.x;
    const float4 v = *(const float4*)(X + (size_t)n * D + tid * 4);
    sh[tid] = v.x + v.y + v.z + v.w;
    __syncthreads();
    for (int st = 128; st > 0; st >>= 1) {
        if (tid < st) sh[tid] += sh[tid + st];
        __syncthreads();
    }
    const float mu = sh[0] * (1.f / D);
    __syncthreads();
    float d0 = v.x - mu, d1 = v.y - mu, d2 = v.z - mu, d3 = v.w - mu;
    sh[tid] = d0 * d0 + d1 * d1 + d2 * d2 + d3 * d3;
    __syncthreads();
    for (int st = 128; st > 0; st >>= 1) {
        if (tid < st) sh[tid] += sh[tid + st];
        __syncthreads();
    }
    const float var = sh[0] * (1.f / D);
    const float rs = rsqrtf(var + 1e-5f);
    const float4 gg = *(const float4*)(g + tid * 4);
    const float4 bb = *(const float4*)(bt + tid * 4);
    float y0 = d0 * rs * gg.x + bb.x;
    float y1 = d1 * rs * gg.y + bb.y;
    float y2 = d2 * rs * gg.z + bb.z;
    float y3 = d3 * rs * gg.w + bb.w;
    ushort4 h, l;
    h.x = f2b(y0); l.x = f2b(y0 - b2f(h.x));
    h.y = f2b(y1); l.y = f2b(y1 - b2f(h.y));
    h.z = f2b(y2); l.z = f2b(y2 - b2f(h.z));
    h.w = f2b(y3); l.w = f2b(y3 - b2f(h.w));
    *(ushort4*)(YH + (size_t)n * D + tid * 4) = h;
    *(ushort4*)(YL + (size_t)n * D + tid * 4) = l;
}

// ---------------- per-token per-head sumsq from hi/lo planes ----------------
__global__ __launch_bounds__(256) void nrm_kernel(const ushort* __restrict__ YH,
                                                  const ushort* __restrict__ YL,
                                                  float* __restrict__ nrm) {
    __shared__ float sh[256];
    const int n = blockIdx.x;
    const int tid = threadIdx.x;
    const ushort4 h = *(const ushort4*)(YH + (size_t)n * D + tid * 4);
    const ushort4 l = *(const ushort4*)(YL + (size_t)n * D + tid * 4);
    float y0 = b2f(h.x) + b2f(l.x);
    float y1 = b2f(h.y) + b2f(l.y);
    float y2 = b2f(h.z) + b2f(l.z);
    float y3 = b2f(h.w) + b2f(l.w);
    sh[tid] = y0 * y0 + y1 * y1 + y2 * y2 + y3 * y3;
    __syncthreads();
    if (tid < NH) {
        float s = 0.f;
        for (int u = 0; u < 16; ++u) s += sh[tid * 16 + u];
        nrm[(size_t)n * NH + tid] = s;
    }
}

// ---------------- leaky-relu + LayerNorm tail (f32) ----------------
__global__ __launch_bounds__(256) void post_kernel(const float* __restrict__ X,
                                                   const float* __restrict__ g,
                                                   const float* __restrict__ bt,
                                                   float* __restrict__ Y) {
    __shared__ float sh[256];
    const int n = blockIdx.x;
    const int tid = threadIdx.x;
    float4 v = *(const float4*)(X + (size_t)n * D + tid * 4);
    v.x = v.x > 0.f ? v.x : 0.01f * v.x;
    v.y = v.y > 0.f ? v.y : 0.01f * v.y;
    v.z = v.z > 0.f ? v.z : 0.01f * v.z;
    v.w = v.w > 0.f ? v.w : 0.01f * v.w;
    sh[tid] = v.x + v.y + v.z + v.w;
    __syncthreads();
    for (int st = 128; st > 0; st >>= 1) {
        if (tid < st) sh[tid] += sh[tid + st];
        __syncthreads();
    }
    const float mu = sh[0] * (1.f / D);
    __syncthreads();
    float d0 = v.x - mu, d1 = v.y - mu, d2 = v.z - mu, d3 = v.w - mu;
    sh[tid] = d0 * d0 + d1 * d1 + d2 * d2 + d3 * d3;
    __syncthreads();
    for (int st = 128; st > 0; st >>= 1) {
        if (tid < st) sh[tid] += sh[tid + st];
        __syncthreads();
    }
    const float var = sh[0] * (1.f / D);
    const float rs = rsqrtf(var + 1e-5f);
    const float4 gg = *(const float4*)(g + tid * 4);
    const float4 bb = *(const float4*)(bt + tid * 4);
    float4 o4;
    o4.x = d0 * rs * gg.x + bb.x;
    o4.y = d1 * rs * gg.y + bb.y;
    o4.z = d2 * rs * gg.z + bb.z;
    o4.w = d3 * rs * gg.w + bb.w;
    *(float4*)(Y + (size_t)n * D + tid * 4) = o4;
}

// ---------------- temporal softmax ----------------
__global__ __launch_bounds__(256) void attn_t_kernel(const float* __restrict__ nrm,
                                                     const float* __restrict__ scal,
                                                     float* __restrict__ attw) {
    int idx = blockIdx.x * 256 + threadIdx.x;
    int p = idx >> 4, h = idx & 15;
    float s = scal[0] * scal[1] * 0.125f;
    float l0 = s * nrm[h];
    float lg[16];
    float mx = l0;
#pragma unroll
    for (int b = 0; b < 16; ++b) {
        float v = s * nrm[(size_t)(1 + p * 16 + b) * NH + h];
        lg[b] = v;
        mx = fmaxf(mx, v);
    }
    float e0 = expf(l0 - mx), Z = e0;
    float eb[16];
#pragma unroll
    for (int b = 0; b < 16; ++b) { eb[b] = expf(lg[b] - mx); Z += eb[b]; }
    float inv = 1.f / Z;
    float* o = attw + (size_t)idx * 17;
    o[0] = e0 * inv;
#pragma unroll
    for (int b = 0; b < 16; ++b) o[1 + b] = eb[b] * inv;
}

// ---------------- spatial softmax ----------------
__global__ __launch_bounds__(256) void attn_s_kernel(const float* __restrict__ nrm,
                                                     const float* __restrict__ scal,
                                                     float* __restrict__ attw) {
    __shared__ float sh[256];
    int bh = blockIdx.x;
    int b = bh >> 4, h = bh & 15;
    int tid = threadIdx.x;
    float s = scal[3] * scal[4] * 0.125f;
    float l0 = s * nrm[h];
    float lv[4];
    float mx = l0;
#pragma unroll
    for (int r = 0; r < 4; ++r) {
        lv[r] = s * nrm[(size_t)(1 + b * 1024 + tid + r * 256) * NH + h];
        mx = fmaxf(mx, lv[r]);
    }
    sh[tid] = mx;
    __syncthreads();
    for (int st = 128; st > 0; st >>= 1) {
        if (tid < st) sh[tid] = fmaxf(sh[tid], sh[tid + st]);
        __syncthreads();
    }
    mx = sh[0];
    __syncthreads();
    float ev[4];
    float z = (tid == 0) ? expf(l0 - mx) : 0.f;
#pragma unroll
    for (int r = 0; r < 4; ++r) { ev[r] = expf(lv[r] - mx); z += ev[r]; }
    sh[tid] = z;
    __syncthreads();
    for (int st = 128; st > 0; st >>= 1) {
        if (tid < st) sh[tid] += sh[tid + st];
        __syncthreads();
    }
    float inv = 1.f / sh[0];
    float* o = attw + (size_t)bh * 1025;
    if (tid == 0) o[0] = expf(l0 - mx) * inv;
#pragma unroll
    for (int r = 0; r < 4; ++r) o[1 + tid + r * 256] = ev[r] * inv;
}

// ---------------- build pre (temporal), in-place on hi/lo planes ----------------
__global__ __launch_bounds__(256) void build_t_kernel(ushort* __restrict__ lnH,
                                                      ushort* __restrict__ lnL,
                                                      const float* __restrict__ attw,
                                                      const float* __restrict__ scal,
                                                      float* __restrict__ tokacc) {
    const float sv = scal[2];
    const int j = blockIdx.y * 256 + threadIdx.x;
    const int h = j >> 6;
    const float l0 = b2f(lnH[j]) + b2f(lnL[j]);
    float tacc = 0.f;
    const int n0 = 1 + blockIdx.x * 64;
    for (int r = 0; r < 64; ++r) {
        int n = n0 + r;
        int pb = n - 1;
        int p = pb >> 4, bb = pb & 15;
        const float* aw = attw + (size_t)(p * NH + h) * 17;
        float w0 = aw[0], wb = aw[1 + bb];
        const size_t idx = (size_t)n * D + j;
        float xv = b2f(lnH[idx]) + b2f(lnL[idx]);
        float pv = sv * (wb * xv + w0 * l0);
        ushort ph = f2b(pv);
        lnH[idx] = ph;
        lnL[idx] = f2b(pv - b2f(ph));
        tacc += w0 * xv;
    }
    atomicAdd(&tokacc[j], tacc);
}

// ---------------- build pre (spatial), in-place on hi/lo planes ----------------
__global__ __launch_bounds__(256) void build_s_kernel(ushort* __restrict__ lnH,
                                                      ushort* __restrict__ lnL,
                                                      const float* __restrict__ attw,
                                                      const float* __restrict__ scal,
                                                      float* __restrict__ tokacc) {
    const float sv = scal[5];
    const int j = blockIdx.y * 256 + threadIdx.x;
    const int h = j >> 6;
    const float l0 = b2f(lnH[j]) + b2f(lnL[j]);
    float tacc = 0.f;
    const int n0 = 1 + blockIdx.x * 64;
    for (int r = 0; r < 64; ++r) {
        int n = n0 + r;
        int pb = n - 1;
        int b = pb >> 10, p = pb & 1023;
        const float* aw = attw + (size_t)(b * NH + h) * 1025;
        float w0 = aw[0], wp = aw[1 + p];
        const size_t idx = (size_t)n * D + j;
        float xv = b2f(lnH[idx]) + b2f(lnL[idx]);
        float pv = sv * (wp * xv + w0 * l0);
        ushort ph = f2b(pv);
        lnH[idx] = ph;
        lnL[idx] = f2b(pv - b2f(ph));
        tacc += w0 * xv;
    }
    atomicAdd(&tokacc[j], tacc);
}

// ---------------- finalize cls row (in-place on planes) ----------------
__global__ __launch_bounds__(256) void fin_tok_kernel(ushort* __restrict__ lnH,
                                                      ushort* __restrict__ lnL,
                                                      const float* __restrict__ tokacc,
                                                      const float* __restrict__ scal,
                                                      int svidx) {
    int j = blockIdx.x * 256 + threadIdx.x;
    float v = scal[svidx] * (b2f(lnH[j]) + b2f(lnL[j]) + tokacc[j]);
    ushort h = f2b(v);
    lnH[j] = h;
    lnL[j] = f2b(v - b2f(h));
}

// ---------------- flat f32 -> hi/lo bf16 ----------------
__global__ __launch_bounds__(256) void cvt_kernel(const float* __restrict__ in,
                                                  ushort* __restrict__ oH,
                                                  ushort* __restrict__ oL) {
    size_t i = ((size_t)blockIdx.x * 256 + threadIdx.x) * 4;
    float4 v = *(const float4*)(in + i);
    ushort4 h, l;
    h.x = f2b(v.x); l.x = f2b(v.x - b2f(h.x));
    h.y = f2b(v.y); l.y = f2b(v.y - b2f(h.y));
    h.z = f2b(v.z); l.z = f2b(v.z - b2f(h.z));
    h.w = f2b(v.w); l.w = f2b(v.w - b2f(h.w));
    *(ushort4*)(oH + i) = h;
    *(ushort4*)(oL + i) = l;
}

// ---------------- f32 [K][1024] -> hi/lo bf16 [1024][K] transpose ----------------
__global__ __launch_bounds__(256) void tcvt_kernel(const float* __restrict__ in,
                                                   ushort* __restrict__ oH,
                                                   ushort* __restrict__ oL) {
    __shared__ float t[32][33];
    const int bi = blockIdx.y, bj = blockIdx.x;
    const int tx = threadIdx.x & 31, ty = threadIdx.x >> 5;
#pragma unroll
    for (int r = 0; r < 4; ++r)
        t[ty * 4 + r][tx] = in[(size_t)(bi * 32 + ty * 4 + r) * 1024 + bj * 32 + tx];
    __syncthreads();
#pragma unroll
    for (int r = 0; r < 4; ++r) {
        float v = t[tx][ty * 4 + r];
        ushort h = f2b(v);
        size_t o = (size_t)(bj * 32 + ty * 4 + r) * 1024 + bi * 32 + tx;
        oH[o] = h;
        oL[o] = f2b(v - b2f(h));
    }
}

// ---------------- bf16x3 MFMA GEMM: C = (AH+AL)@(BH+BL)^T (+bias) + E ----------------
// 128x128 tile, BK=32, 4 waves 2x2, wave = 64x64 out. 48 MFMA / K-step.
template <int HAS_BIAS>
__global__ __launch_bounds__(256) void gemm3(const ushort* __restrict__ AH,
                                             const ushort* __restrict__ AL,
                                             const ushort* __restrict__ BH,
                                             const ushort* __restrict__ BL,
                                             const float* __restrict__ bias,
                                             const float* __restrict__ E,
                                             float* __restrict__ C,
                                             int M, int K) {
    __shared__ ushort AsH[128 * 32], AsL[128 * 32], BsH[128 * 32], BsL[128 * 32];
    const int tid = threadIdx.x;
    const int lane = tid & 63;
    const int wave = tid >> 6;
    const int wr = wave >> 1, wc = wave & 1;
    const int l15 = lane & 15, l16 = lane >> 4;
    const int r0 = blockIdx.y * 128;
    const int c0 = blockIdx.x * 128;

    f32x4 acc[4][4];
#pragma unroll
    for (int m = 0; m < 4; ++m)
#pragma unroll
        for (int n = 0; n < 4; ++n) acc[m][n] = (f32x4){0.f, 0.f, 0.f, 0.f};

    const int srow = tid >> 2;
    const int skk = (tid & 3) * 8;

    for (int k0 = 0; k0 < K; k0 += 32) {
        __syncthreads();
#pragma unroll
        for (int j = 0; j < 2; ++j) {
            int ar = r0 + j * 64 + srow;
            if (ar > M - 1) ar = M - 1;
            const size_t off = (size_t)ar * K + k0 + skk;
            const size_t dst = ((size_t)j * 256 + tid) * 8;
            gload_lds16(AH + off, AsH + dst);
            gload_lds16(AL + off, AsL + dst);
        }
#pragma unroll
        for (int j = 0; j < 2; ++j) {
            int br = c0 + j * 64 + srow;
            const size_t off = (size_t)br * K + k0 + skk;
            const size_t dst = ((size_t)j * 256 + tid) * 8;
            gload_lds16(BH + off, BsH + dst);
            gload_lds16(BL + off, BsL + dst);
        }
        __syncthreads();

        bf16x8 ah[4], al[4], bh[4], bl[4];
#pragma unroll
        for (int m = 0; m < 4; ++m) {
            const int o = (wr * 64 + m * 16 + l15) * 32 + l16 * 8;
            ah[m] = *(const bf16x8*)(AsH + o);
            al[m] = *(const bf16x8*)(AsL + o);
        }
#pragma unroll
        for (int n = 0; n < 4; ++n) {
            const int o = (wc * 64 + n * 16 + l15) * 32 + l16 * 8;
            bh[n] = *(const bf16x8*)(BsH + o);
            bl[n] = *(const bf16x8*)(BsL + o);
        }
#pragma unroll
        for (int m = 0; m < 4; ++m)
#pragma unroll
            for (int n = 0; n < 4; ++n) {
                acc[m][n] = __builtin_amdgcn_mfma_f32_16x16x32_bf16(ah[m], bh[n], acc[m][n], 0, 0, 0);
                acc[m][n] = __builtin_amdgcn_mfma_f32_16x16x32_bf16(al[m], bh[n], acc[m][n], 0, 0, 0);
                acc[m][n] = __builtin_amdgcn_mfma_f32_16x16x32_bf16(ah[m], bl[n], acc[m][n], 0, 0, 0);
            }
    }

#pragma unroll
    for (int m = 0; m < 4; ++m) {
        const int rb = r0 + wr * 64 + m * 16 + l16 * 4;
#pragma unroll
        for (int n = 0; n < 4; ++n) {
            const int col = c0 + wc * 64 + n * 16 + l15;
            const float bv = HAS_BIAS ? bias[col] : 0.f;
#pragma unroll
            for (int reg = 0; reg < 4; ++reg) {
                const int r = rb + reg;
                if (r < M) {
                    const size_t idx = (size_t)r * 1024 + col;
                    C[idx] = acc[m][n][reg] + bv + E[idx];
                }
            }
        }
    }
}

extern "C" void kernel_launch(void* const* d_in, const int* in_sizes, int n_in,
                              void* d_out, int out_size, void* d_ws, size_t ws_size,
                              hipStream_t stream) {
    const float* x       = (const float*)d_in[0];
    const float* cls     = (const float*)d_in[1];
    const float* w_embed = (const float*)d_in[2];
    const float* pos_enc = (const float*)d_in[3];
    const float* ln_t_g  = (const float*)d_in[4];
    const float* ln_t_b  = (const float*)d_in[5];
    const float* wq_t    = (const float*)d_in[6];
    const float* wk_t    = (const float*)d_in[7];
    const float* wv_t    = (const float*)d_in[8];
    const float* wt_t    = (const float*)d_in[9];
    const float* ln_s_g  = (const float*)d_in[10];
    const float* ln_s_b  = (const float*)d_in[11];
    const float* wq_s    = (const float*)d_in[12];
    const float* wk_s    = (const float*)d_in[13];
    const float* wv_s    = (const float*)d_in[14];
    const float* wt_s    = (const float*)d_in[15];
    const float* ln_m_g  = (const float*)d_in[16];
    const float* ln_m_b  = (const float*)d_in[17];
    const float* mlp_w   = (const float*)d_in[18];
    const float* mlp_b   = (const float*)d_in[19];
    const float* out_g   = (const float*)d_in[20];
    const float* out_b   = (const float*)d_in[21];

    const size_t BIG = (size_t)NTOK * D;
    float* ws = (float*)d_ws;
    float* bufA = ws;                              // f32 residual stream
    ushort* aH = (ushort*)(bufA + BIG);            // bf16 hi plane (LN out / pre / A-op)
    ushort* aL = aH + BIG;                         // bf16 lo plane
    ushort* wH = aL + BIG;                         // weight hi [1024*1024]
    ushort* wL = wH + (size_t)D * D;               // weight lo
    float* nrm = (float*)(wL + (size_t)D * D);
    float* attw = nrm + (size_t)NTOK * NH;
    float* tokacc = attw + 278528;
    float* scal = tokacc + 1024;
    size_t need = (size_t)((char*)(scal + 8) - (char*)ws);
    if (ws_size < need) return;

    float* fout = (float*)d_out;

    // ---- embed: patches @ w_embed^T + pos_enc ----
    patchify_kernel<<<12288, 256, 0, stream>>>(x, aH, aL);
    cls_kernel<<<1, 256, 0, stream>>>(cls, bufA);
    cvt_kernel<<<768, 256, 0, stream>>>(w_embed, wH, wL);     // [1024][768] native B^T
    gemm3<0><<<dim3(8, 128), 256, 0, stream>>>(aH, aL, wH, wL, nullptr, pos_enc,
                                               bufA + D, NPATCH, 768);

    const dim3 ggrid(8, (NTOK + 127) / 128);
    for (int l = 0; l < 4; ++l) {
        const size_t oW = (size_t)l * D * D;
        const size_t oS = (size_t)l * NH * HD * HD;
        const size_t oD = (size_t)l * D;
        sums6_kernel<<<6, 256, 0, stream>>>(wq_t + oS, wk_t + oS, wv_t + oS,
                                            wq_s + oS, wk_s + oS, wv_s + oS, scal);
        // temporal
        ln_split_kernel<<<NTOK, 256, 0, stream>>>(bufA, ln_t_g + oD, ln_t_b + oD, aH, aL);
        nrm_kernel<<<NTOK, 256, 0, stream>>>(aH, aL, nrm);
        zero_kernel<<<4, 256, 0, stream>>>(tokacc);
        attn_t_kernel<<<64, 256, 0, stream>>>(nrm, scal, attw);
        build_t_kernel<<<dim3(256, 4), 256, 0, stream>>>(aH, aL, attw, scal, tokacc);
        fin_tok_kernel<<<4, 256, 0, stream>>>(aH, aL, tokacc, scal, 2);
        tcvt_kernel<<<dim3(32, 32), 256, 0, stream>>>(wt_t + oW, wH, wL);
        gemm3<0><<<ggrid, 256, 0, stream>>>(aH, aL, wH, wL, nullptr, bufA, bufA, NTOK, 1024);
        // spatial
        ln_split_kernel<<<NTOK, 256, 0, stream>>>(bufA, ln_s_g + oD, ln_s_b + oD, aH, aL);
        nrm_kernel<<<NTOK, 256, 0, stream>>>(aH, aL, nrm);
        zero_kernel<<<4, 256, 0, stream>>>(tokacc);
        attn_s_kernel<<<256, 256, 0, stream>>>(nrm, scal, attw);
        build_s_kernel<<<dim3(256, 4), 256, 0, stream>>>(aH, aL, attw, scal, tokacc);
        fin_tok_kernel<<<4, 256, 0, stream>>>(aH, aL, tokacc, scal, 5);
        tcvt_kernel<<<dim3(32, 32), 256, 0, stream>>>(wt_s + oW, wH, wL);
        gemm3<0><<<ggrid, 256, 0, stream>>>(aH, aL, wH, wL, nullptr, bufA, bufA, NTOK, 1024);
        // mlp + tail
        ln_split_kernel<<<NTOK, 256, 0, stream>>>(bufA, ln_m_g + oD, ln_m_b + oD, aH, aL);
        cvt_kernel<<<1024, 256, 0, stream>>>(mlp_w + oW, wH, wL);        // [N][K] native B^T
        gemm3<1><<<ggrid, 256, 0, stream>>>(aH, aL, wH, wL, mlp_b + oD, bufA, bufA, NTOK, 1024);
        post_kernel<<<NTOK, 256, 0, stream>>>(bufA, out_g + oD, out_b + oD,
                                              (l == 3) ? fout : bufA);
    }
}